// Round 9
// baseline (128.756 us; speedup 1.0000x reference)
//
#include <hip/hip_runtime.h>

#define SQRT2f 1.41421356237309515f
#define SQRT3f 1.73205080756887729f

__device__ __forceinline__ float2 cmul(float2 a, float2 b) {
  return make_float2(a.x*b.x - a.y*b.y, a.x*b.y + a.y*b.x);
}
__device__ __forceinline__ float2 cadd(float2 a, float2 b) {
  return make_float2(a.x + b.x, a.y + b.y);
}

// ---- BS 9x9 on a register 9-vector q[3*na+nb] (rows 0,8 identity) ----
__device__ __forceinline__ void bs_q(float2 q[9], float c, float s,
                                     float c2, float s2, float cc, float ss,
                                     float rcs) {
  float2 a1=q[1], a3=q[3], a2=q[2], a4=q[4], a6=q[6], a5=q[5], a7=q[7];
  q[1] = make_float2(c*a1.x - s*a3.x, c*a1.y - s*a3.y);
  q[3] = make_float2(s*a1.x + c*a3.x, s*a1.y + c*a3.y);
  q[2] = make_float2(cc*a2.x - rcs*a4.x + ss*a6.x, cc*a2.y - rcs*a4.y + ss*a6.y);
  q[4] = make_float2(rcs*a2.x + c2*a4.x - rcs*a6.x, rcs*a2.y + c2*a4.y - rcs*a6.y);
  q[6] = make_float2(ss*a2.x + rcs*a4.x + cc*a6.x, ss*a2.y + rcs*a4.y + cc*a6.y);
  q[5] = make_float2(c2*a5.x - s2*a7.x, c2*a5.y - s2*a7.y);
  q[7] = make_float2(s2*a5.x + c2*a7.x, s2*a5.y + c2*a7.y);
}

// ---- 2-state plain BS nonet, in place: reads both, computes both, writes both ----
template<int SP>
__device__ __forceinline__ void bs_nonet2(float2* __restrict__ pA,
                                          float2* __restrict__ pB,
                                          int base, float2 cs) {
  const float c = cs.x, s = cs.y;
  const float c2 = c*c - s*s, s2 = 2.f*c*s;
  const float cc = c*c, ss = s*s, rcs = SQRT2f*c*s;
  float2 A1 = pA[base+SP],   A3 = pA[base+3*SP];
  float2 A2 = pA[base+2*SP], A4 = pA[base+4*SP], A6 = pA[base+6*SP];
  float2 A5 = pA[base+5*SP], A7 = pA[base+7*SP];
  float2 B1 = pB[base+SP],   B3 = pB[base+3*SP];
  float2 B2 = pB[base+2*SP], B4 = pB[base+4*SP], B6 = pB[base+6*SP];
  float2 B5 = pB[base+5*SP], B7 = pB[base+7*SP];
  pA[base+SP]   = make_float2(c*A1.x - s*A3.x, c*A1.y - s*A3.y);
  pA[base+3*SP] = make_float2(s*A1.x + c*A3.x, s*A1.y + c*A3.y);
  pA[base+2*SP] = make_float2(cc*A2.x - rcs*A4.x + ss*A6.x,
                              cc*A2.y - rcs*A4.y + ss*A6.y);
  pA[base+4*SP] = make_float2(rcs*A2.x + c2*A4.x - rcs*A6.x,
                              rcs*A2.y + c2*A4.y - rcs*A6.y);
  pA[base+6*SP] = make_float2(ss*A2.x + rcs*A4.x + cc*A6.x,
                              ss*A2.y + rcs*A4.y + cc*A6.y);
  pA[base+5*SP] = make_float2(c2*A5.x - s2*A7.x, c2*A5.y - s2*A7.y);
  pA[base+7*SP] = make_float2(s2*A5.x + c2*A7.x, s2*A5.y + c2*A7.y);
  pB[base+SP]   = make_float2(c*B1.x - s*B3.x, c*B1.y - s*B3.y);
  pB[base+3*SP] = make_float2(s*B1.x + c*B3.x, s*B1.y + c*B3.y);
  pB[base+2*SP] = make_float2(cc*B2.x - rcs*B4.x + ss*B6.x,
                              cc*B2.y - rcs*B4.y + ss*B6.y);
  pB[base+4*SP] = make_float2(rcs*B2.x + c2*B4.x - rcs*B6.x,
                              rcs*B2.y + c2*B4.y - rcs*B6.y);
  pB[base+6*SP] = make_float2(ss*B2.x + rcs*B4.x + cc*B6.x,
                              ss*B2.y + rcs*B4.y + cc*B6.y);
  pB[base+5*SP] = make_float2(c2*B5.x - s2*B7.x, c2*B5.y - s2*B7.y);
  pB[base+7*SP] = make_float2(s2*B5.x + c2*B7.x, s2*B5.y + c2*B7.y);
}

// ---- 2-state fused (A dense ⊗ B dense) then BS. G = A(9),B(9) ----
template<int SP>
__device__ __forceinline__ void dpbs_nonet2(float2* __restrict__ pA,
                                            float2* __restrict__ pB,
                                            int base,
                                            const float2* __restrict__ G,
                                            float2 cs) {
  const float c = cs.x, s = cs.y;
  const float c2 = c*c - s*s, s2 = 2.f*c*s;
  const float cc = c*c, ss = s*s, rcs = SQRT2f*c*s;
  const float2* A = G; const float2* B = G + 9;
  float2 vA[3][3], vB[3][3];
#pragma unroll
  for (int j = 0; j < 3; ++j)
#pragma unroll
    for (int jb = 0; jb < 3; ++jb) {
      vA[j][jb] = pA[base + j*3*SP + jb*SP];
      vB[j][jb] = pB[base + j*3*SP + jb*SP];
    }
  float2 qA[9], qB[9];
  {
    float2 t[3][3];
#pragma unroll
    for (int j = 0; j < 3; ++j)
#pragma unroll
      for (int ib = 0; ib < 3; ++ib)
        t[j][ib] = cadd(cadd(cmul(B[ib*3+0],vA[j][0]), cmul(B[ib*3+1],vA[j][1])),
                        cmul(B[ib*3+2],vA[j][2]));
#pragma unroll
    for (int i = 0; i < 3; ++i)
#pragma unroll
      for (int ib = 0; ib < 3; ++ib)
        qA[i*3+ib] = cadd(cadd(cmul(A[i*3+0],t[0][ib]), cmul(A[i*3+1],t[1][ib])),
                          cmul(A[i*3+2],t[2][ib]));
  }
  {
    float2 t[3][3];
#pragma unroll
    for (int j = 0; j < 3; ++j)
#pragma unroll
      for (int ib = 0; ib < 3; ++ib)
        t[j][ib] = cadd(cadd(cmul(B[ib*3+0],vB[j][0]), cmul(B[ib*3+1],vB[j][1])),
                        cmul(B[ib*3+2],vB[j][2]));
#pragma unroll
    for (int i = 0; i < 3; ++i)
#pragma unroll
      for (int ib = 0; ib < 3; ++ib)
        qB[i*3+ib] = cadd(cadd(cmul(A[i*3+0],t[0][ib]), cmul(A[i*3+1],t[1][ib])),
                          cmul(A[i*3+2],t[2][ib]));
  }
  bs_q(qA, c, s, c2, s2, cc, ss, rcs);
  bs_q(qB, c, s, c2, s2, cc, ss, rcs);
#pragma unroll
  for (int i = 0; i < 9; ++i) {
    pA[base + (i/3)*3*SP + (i%3)*SP] = qA[i];
    pB[base + (i/3)*3*SP + (i%3)*SP] = qB[i];
  }
}

// ---- 2-state fused (sparse SQ ⊗ sparse SQ) then BS. G = A(5),B(5) ----
template<int SP>
__device__ __forceinline__ void sqbs_nonet2(float2* __restrict__ pA,
                                            float2* __restrict__ pB,
                                            int base,
                                            const float2* __restrict__ G,
                                            float2 cs) {
  const float c = cs.x, s = cs.y;
  const float c2 = c*c - s*s, s2 = 2.f*c*s;
  const float cc = c*c, ss = s*s, rcs = SQRT2f*c*s;
  float2 A00=G[0],A02=G[1],A11=G[2],A20=G[3],A22=G[4];
  float2 B00=G[5],B02=G[6],B11=G[7],B20=G[8],B22=G[9];
  float2 vA[3][3], vB[3][3];
#pragma unroll
  for (int j = 0; j < 3; ++j)
#pragma unroll
    for (int jb = 0; jb < 3; ++jb) {
      vA[j][jb] = pA[base + j*3*SP + jb*SP];
      vB[j][jb] = pB[base + j*3*SP + jb*SP];
    }
  float2 qA[9], qB[9];
  {
    float2 t[3][3];
#pragma unroll
    for (int j = 0; j < 3; ++j) {
      t[j][0] = cadd(cmul(B00,vA[j][0]), cmul(B02,vA[j][2]));
      t[j][1] = cmul(B11,vA[j][1]);
      t[j][2] = cadd(cmul(B20,vA[j][0]), cmul(B22,vA[j][2]));
    }
#pragma unroll
    for (int ib = 0; ib < 3; ++ib) {
      qA[ib]   = cadd(cmul(A00,t[0][ib]), cmul(A02,t[2][ib]));
      qA[3+ib] = cmul(A11,t[1][ib]);
      qA[6+ib] = cadd(cmul(A20,t[0][ib]), cmul(A22,t[2][ib]));
    }
  }
  {
    float2 t[3][3];
#pragma unroll
    for (int j = 0; j < 3; ++j) {
      t[j][0] = cadd(cmul(B00,vB[j][0]), cmul(B02,vB[j][2]));
      t[j][1] = cmul(B11,vB[j][1]);
      t[j][2] = cadd(cmul(B20,vB[j][0]), cmul(B22,vB[j][2]));
    }
#pragma unroll
    for (int ib = 0; ib < 3; ++ib) {
      qB[ib]   = cadd(cmul(A00,t[0][ib]), cmul(A02,t[2][ib]));
      qB[3+ib] = cmul(A11,t[1][ib]);
      qB[6+ib] = cadd(cmul(A20,t[0][ib]), cmul(A22,t[2][ib]));
    }
  }
  bs_q(qA, c, s, c2, s2, cc, ss, rcs);
  bs_q(qB, c, s, c2, s2, cc, ss, rcs);
#pragma unroll
  for (int i = 0; i < 9; ++i) {
    pA[base + (i/3)*3*SP + (i%3)*SP] = qA[i];
    pB[base + (i/3)*3*SP + (i%3)*SP] = qB[i];
  }
}

#define BASE4(g, s0,s1,s2,s3) ({ int _d=(g); int _b=(_d%3)*(s0); _d/=3; \
  _b += (_d%3)*(s1); _d/=3; _b += (_d%3)*(s2); _d/=3; _b += (_d%3)*(s3); _b; })
#define BASE5(g, s0,s1,s2,s3,s4) ({ int _d=(g); int _b=(_d%3)*(s0); _d/=3; \
  _b += (_d%3)*(s1); _d/=3; _b += (_d%3)*(s2); _d/=3; _b += (_d%3)*(s3); _d/=3; \
  _b += (_d%3)*(s4); _b; })

// DPK(L,mode)[i][j] = Kerr_i * U_disp[i][j] * phase^j (th2-layer phases)
__device__ __forceinline__ float2 dpk_entry(const float* __restrict__ dr,
                                            const float* __restrict__ th2,
                                            const float* __restrict__ kp,
                                            int L, int mode, int i, int j) {
  float sn, cn; sincosf(SQRT3f*dr[L*6+mode], &sn, &cn);
  float sw = sn*(1.f/SQRT3f), cw = (1.f-cn)*(1.f/3.f);
  float U;
  if      (i==0) U = (j==0) ? (1.f-cw)     : (j==1) ? (-sw)         : (SQRT2f*cw);
  else if (i==1) U = (j==0) ? (sw)         : (j==1) ? (1.f-3.f*cw)  : (-SQRT2f*sw);
  else           U = (j==0) ? (SQRT2f*cw)  : (j==1) ? (SQRT2f*sw)   : (1.f-2.f*cw);
  float2 ph = make_float2(1.f, 0.f);
  if (mode < 5) { float ps, pc; sincosf(th2[L*35+29+mode], &ps, &pc);
                  ph = make_float2(pc, ps); }
  float2 phj = (j==0) ? make_float2(1.f,0.f) : (j==1) ? ph : cmul(ph, ph);
  float ks, kc; sincosf(0.001f*kp[L*6+mode], &ks, &kc);
  float2 k1 = make_float2(kc, ks);
  float2 ki = (i==0) ? make_float2(1.f,0.f)
            : (i==1) ? k1 : cmul(cmul(k1,k1), cmul(k1,k1));
  float2 t = cmul(phj, ki);
  return make_float2(U*t.x, U*t.y);
}

// gtab (float2):
// [0,180)   BS (c,s): idx = (L*2+pass)*15 + pos (application order)
// [180,360) SQG: 180 + (L*3+c)*10 : A(5) mode 2c, B(5) mode 2c+1 (th1 phases)
// [360,630) DPG: 360 + (Ls*3+c)*18 : A(9) mode 2c, B(9) mode 2c+1 (layers 0..4)
// [630,684) Meas M_m = DPK(5,m)† X3 DPK(5,m): 630 + m*9 + i*3+j
// [684,696) init disp (sw,cw): 684 + st*6 + mode
__global__ __launch_bounds__(128)
void cvnn_kernel(const float* __restrict__ x,
                 const float* __restrict__ th1,
                 const float* __restrict__ th2,
                 const float* __restrict__ sr,
                 const float* __restrict__ dr,
                 const float* __restrict__ kp,
                 float* __restrict__ out, int Btot) {
  __shared__ float2 psiA[729];
  __shared__ float2 psiB[729];
  __shared__ float2 gtab[696];
  __shared__ float red[24];

  const int tid = threadIdx.x;
  const int bidx = blockIdx.x;

  // ---- build gate table ----
  for (int f = tid; f < 696; f += 128) {
    float sn, cn; float2 v;
    if (f < 180) {
      int Lp = f/15, pos = f%15;
      int L = Lp/2, pass = Lp%2;
      float th = (pass ? th2 : th1)[L*35 + pos];
      sincosf(th, &sn, &cn); v = make_float2(cn, sn);
    } else if (f < 360) {
      int i = f - 180; int Lc = i/10, e = i%10;
      int L = Lc/3, c3 = Lc%3;
      int mode = 2*c3 + (e >= 5); int ee = e%5;
      float Sq, Cq; sincosf(0.25f*SQRT2f*sr[L*6+mode], &Sq, &Cq);
      float2 ph = make_float2(1.f, 0.f);
      if (mode < 5) { float ps, pc; sincosf(th1[L*35+29+mode], &ps, &pc);
                      ph = make_float2(pc, ps); }
      float2 ph2 = cmul(ph, ph);
      if      (ee == 0) v = make_float2(Cq, 0.f);
      else if (ee == 1) v = make_float2(Sq*ph2.x, Sq*ph2.y);
      else if (ee == 2) v = ph;
      else if (ee == 3) v = make_float2(-Sq, 0.f);
      else              v = make_float2(Cq*ph2.x, Cq*ph2.y);
    } else if (f < 630) {
      int i = f - 360; int Ld = i/18, e = i%18;
      int Ls = Ld/3, c3 = Ld%3;
      int mode = 2*c3 + (e >= 9); int ee = e%9;
      v = dpk_entry(dr, th2, kp, Ls, mode, ee/3, ee%3);
    } else if (f < 684) {
      int i = f - 630; int m = i/9, e = i%9;
      int ii = e/3, jj = e%3;
      float2 D0i = dpk_entry(dr, th2, kp, 5, m, 0, ii);
      float2 D1i = dpk_entry(dr, th2, kp, 5, m, 1, ii);
      float2 D2i = dpk_entry(dr, th2, kp, 5, m, 2, ii);
      float2 D0j = dpk_entry(dr, th2, kp, 5, m, 0, jj);
      float2 D1j = dpk_entry(dr, th2, kp, 5, m, 1, jj);
      float2 D2j = dpk_entry(dr, th2, kp, 5, m, 2, jj);
      float2 c0 = make_float2(D0i.x, -D0i.y);
      float2 c1 = make_float2(D1i.x, -D1i.y);
      float2 c2 = make_float2(D2i.x, -D2i.y);
      float2 acc = cmul(c0, D1j);
      float2 tmp = make_float2(D0j.x + SQRT2f*D2j.x, D0j.y + SQRT2f*D2j.y);
      acc = cadd(acc, cmul(c1, tmp));
      acc = cadd(acc, cmul(c2, make_float2(SQRT2f*D1j.x, SQRT2f*D1j.y)));
      v = acc;
    } else {
      int i = f - 684; int st = i/6, mode = i%6;
      int b = bidx*2 + st; if (b >= Btot) b = Btot - 1;
      sincosf(SQRT3f*x[b*6 + mode], &sn, &cn);
      v = make_float2(sn*(1.f/SQRT3f), (1.f-cn)*(1.f/3.f));
    }
    gtab[f] = v;
  }
  __syncthreads();

  // ---- init: product state of displaced |0>, both states ----
  for (int idx = tid; idx < 729; idx += 128) {
    float prA = 1.f, prB = 1.f; int d = idx;
#pragma unroll
    for (int mm = 5; mm >= 0; --mm) {
      int n = d % 3; d /= 3;
      float2 dA = gtab[684 + mm];
      float2 dB = gtab[690 + mm];
      prA *= (n==0) ? (1.f-dA.y) : (n==1) ? dA.x : SQRT2f*dA.y;
      prB *= (n==0) ? (1.f-dB.y) : (n==1) ? dB.x : SQRT2f*dB.y;
    }
    psiA[idx] = make_float2(prA, 0.f);
    psiB[idx] = make_float2(prB, 0.f);
  }

  // ---- per-thread nonet bases (tid < 81 active) ----
  const bool act = (tid < 81);
  const int g = (tid < 81) ? tid : 0;
  const int b0 = g;                          // k=0 SP=81
  const int b1 = BASE4(g, 1, 3, 9, 243);     // k=1 SP=27
  const int b2 = BASE4(g, 1, 3, 81, 243);    // k=2 SP=9
  const int b3 = BASE4(g, 1, 27, 81, 243);   // k=3 SP=3
  const int b4 = BASE4(g, 9, 27, 81, 243);   // k=4 SP=1
  __syncthreads();

  float2 csN = gtab[0];   // prefetch first sweep's (c,s)
  __syncthreads();

#define BSP(SP, BB, NEXT)  { if (act) bs_nonet2<SP>(psiA, psiB, BB, csN); \
    csN = gtab[NEXT]; __syncthreads(); }
#define DPBS(SP, BB, GI, NEXT) { if (act) dpbs_nonet2<SP>(psiA, psiB, BB, &gtab[GI], csN); \
    csN = gtab[NEXT]; __syncthreads(); }
#define SQBS(SP, BB, GI, NEXT) { if (act) sqbs_nonet2<SP>(psiA, psiB, BB, &gtab[GI], csN); \
    csN = gtab[NEXT]; __syncthreads(); }

#pragma unroll
  for (int L = 0; L < 6; ++L) {
    const int i1 = (L*2)*15, i2 = (L*2+1)*15;
    // pass 1: first course folds previous layer's DPK (L>=1)
    if (L == 0) {
      BSP(81, b0, i1+1); BSP(9, b2, i1+2); BSP(1, b4, i1+3);
    } else {
      const int gd = 360 + (L-1)*3*18;
      DPBS(81, b0, gd+0,  i1+1); DPBS(9, b2, gd+18, i1+2); DPBS(1, b4, gd+36, i1+3);
    }
    BSP(27, b1, i1+4);  BSP(3, b3, i1+5);
    BSP(81, b0, i1+6);  BSP(9, b2, i1+7);  BSP(1, b4, i1+8);
    BSP(27, b1, i1+9);  BSP(3, b3, i1+10);
    BSP(81, b0, i1+11); BSP(9, b2, i1+12); BSP(1, b4, i1+13);
    BSP(27, b1, i1+14); BSP(3, b3, i2+0);
    // pass 2: first course folds this layer's SQ (+th1 phases)
    {
      const int gs = 180 + L*3*10;
      SQBS(81, b0, gs+0, i2+1); SQBS(9, b2, gs+10, i2+2); SQBS(1, b4, gs+20, i2+3);
    }
    BSP(27, b1, i2+4);  BSP(3, b3, i2+5);
    BSP(81, b0, i2+6);  BSP(9, b2, i2+7);  BSP(1, b4, i2+8);
    BSP(27, b1, i2+9);  BSP(3, b3, i2+10);
    BSP(81, b0, i2+11); BSP(9, b2, i2+12); BSP(1, b4, i2+13);
    BSP(27, b1, i2+14); BSP(3, b3, (L < 5) ? (L+1)*30 : 0);
  }

  // ---- <X_m> via folded Hermitian M_m = DPK† X DPK, both states ----
  float xsA[6] = {0.f,0.f,0.f,0.f,0.f,0.f};
  float xsB[6] = {0.f,0.f,0.f,0.f,0.f,0.f};
  for (int it = 0; it < 2; ++it) {
    int t = tid + (it << 7);
    if (t < 243) {
#define XACC2(m, SS, BB) { int b_ = (BB); \
      const float2* M_ = &gtab[630 + (m)*9]; \
      float d0 = M_[0].x, d1 = M_[4].x, d2 = M_[8].x; \
      float2 M01 = M_[1], M02 = M_[2], M12 = M_[5]; \
      { float2 a_ = psiA[b_]; float2 e_ = psiA[b_+(SS)]; float2 f_ = psiA[b_+2*(SS)]; \
        xsA[m] += d0*(a_.x*a_.x + a_.y*a_.y) + d1*(e_.x*e_.x + e_.y*e_.y) \
               + d2*(f_.x*f_.x + f_.y*f_.y) \
          + 2.f*(M01.x*(a_.x*e_.x + a_.y*e_.y) - M01.y*(a_.x*e_.y - a_.y*e_.x)) \
          + 2.f*(M02.x*(a_.x*f_.x + a_.y*f_.y) - M02.y*(a_.x*f_.y - a_.y*f_.x)) \
          + 2.f*(M12.x*(e_.x*f_.x + e_.y*f_.y) - M12.y*(e_.x*f_.y - e_.y*f_.x)); } \
      { float2 a_ = psiB[b_]; float2 e_ = psiB[b_+(SS)]; float2 f_ = psiB[b_+2*(SS)]; \
        xsB[m] += d0*(a_.x*a_.x + a_.y*a_.y) + d1*(e_.x*e_.x + e_.y*e_.y) \
               + d2*(f_.x*f_.x + f_.y*f_.y) \
          + 2.f*(M01.x*(a_.x*e_.x + a_.y*e_.y) - M01.y*(a_.x*e_.y - a_.y*e_.x)) \
          + 2.f*(M02.x*(a_.x*f_.x + a_.y*f_.y) - M02.y*(a_.x*f_.y - a_.y*f_.x)) \
          + 2.f*(M12.x*(e_.x*f_.x + e_.y*f_.y) - M12.y*(e_.x*f_.y - e_.y*f_.x)); } }
      XACC2(0, 243, BASE5(t, 1, 3, 9, 27, 81));
      XACC2(1, 81,  BASE5(t, 1, 3, 9, 27, 243));
      XACC2(2, 27,  BASE5(t, 1, 3, 9, 81, 243));
      XACC2(3, 9,   BASE5(t, 1, 3, 27, 81, 243));
      XACC2(4, 3,   BASE5(t, 1, 9, 27, 81, 243));
      XACC2(5, 1,   BASE5(t, 3, 9, 27, 81, 243));
    }
  }
  const int lane = tid & 63, wid = tid >> 6;
#pragma unroll
  for (int m = 0; m < 6; ++m) {
    float vA = xsA[m], vB = xsB[m];
    for (int off = 32; off > 0; off >>= 1) {
      vA += __shfl_down(vA, off); vB += __shfl_down(vB, off);
    }
    if (lane == 0) { red[wid*6 + m] = vA; red[12 + wid*6 + m] = vB; }
  }
  __syncthreads();
  if (tid < 12) {
    int st = tid/6, m = tid%6;
    float v = red[st*12 + m] + red[st*12 + 6 + m];
    int b = bidx*2 + st;
    if (b < Btot) out[b*6 + m] = v;
  }
}

extern "C" void kernel_launch(void* const* d_in, const int* in_sizes, int n_in,
                              void* d_out, int out_size, void* d_ws, size_t ws_size,
                              hipStream_t stream) {
  const float* x  = (const float*)d_in[0];
  const float* t1 = (const float*)d_in[1];
  const float* t2 = (const float*)d_in[2];
  const float* sr = (const float*)d_in[3];
  const float* dr = (const float*)d_in[4];
  const float* kp = (const float*)d_in[5];
  const int B = in_sizes[0] / 6;
  const int nb = (B + 1) / 2;
  cvnn_kernel<<<nb, 128, 0, stream>>>(x, t1, t2, sr, dr, kp, (float*)d_out, B);
}

// Round 10
// 109.074 us; speedup vs baseline: 1.1805x; 1.1805x over previous
//
#include <hip/hip_runtime.h>

#define SQRT2f 1.41421356237309515f
#define SQRT3f 1.73205080756887729f

__device__ __forceinline__ float2 cmul(float2 a, float2 b) {
  return make_float2(a.x*b.x - a.y*b.y, a.x*b.y + a.y*b.x);
}
__device__ __forceinline__ float2 cadd(float2 a, float2 b) {
  return make_float2(a.x + b.x, a.y + b.y);
}

// ---- BS 9x9 on a register 9-vector q[3*nk + nk1] (rows 0,8 identity) ----
__device__ __forceinline__ void bs_q(float2* q, float c, float s,
                                     float c2, float s2, float cc, float ss,
                                     float rcs) {
  float2 a1=q[1], a3=q[3], a2=q[2], a4=q[4], a6=q[6], a5=q[5], a7=q[7];
  q[1] = make_float2(c*a1.x - s*a3.x, c*a1.y - s*a3.y);
  q[3] = make_float2(s*a1.x + c*a3.x, s*a1.y + c*a3.y);
  q[2] = make_float2(cc*a2.x - rcs*a4.x + ss*a6.x, cc*a2.y - rcs*a4.y + ss*a6.y);
  q[4] = make_float2(rcs*a2.x + c2*a4.x - rcs*a6.x, rcs*a2.y + c2*a4.y - rcs*a6.y);
  q[6] = make_float2(ss*a2.x + rcs*a4.x + cc*a6.x, ss*a2.y + rcs*a4.y + cc*a6.y);
  q[5] = make_float2(c2*a5.x - s2*a7.x, c2*a5.y - s2*a7.y);
  q[7] = make_float2(s2*a5.x + c2*a7.x, s2*a5.y + c2*a7.y);
}

// ---- plain BS nonet (pair 0,1; SP=81), in place ----
template<int SP>
__device__ __forceinline__ void bs_nonet(float2* __restrict__ psi, int base,
                                         float2 cs) {
  const float c = cs.x, s = cs.y;
  const float c2 = c*c - s*s, s2 = 2.f*c*s;
  const float cc = c*c, ss = s*s, rcs = SQRT2f*c*s;
  float2 a1 = psi[base+SP],   a3 = psi[base+3*SP];
  float2 a2 = psi[base+2*SP], a4 = psi[base+4*SP], a6 = psi[base+6*SP];
  float2 a5 = psi[base+5*SP], a7 = psi[base+7*SP];
  psi[base+SP]   = make_float2(c*a1.x - s*a3.x, c*a1.y - s*a3.y);
  psi[base+3*SP] = make_float2(s*a1.x + c*a3.x, s*a1.y + c*a3.y);
  psi[base+2*SP] = make_float2(cc*a2.x - rcs*a4.x + ss*a6.x,
                               cc*a2.y - rcs*a4.y + ss*a6.y);
  psi[base+4*SP] = make_float2(rcs*a2.x + c2*a4.x - rcs*a6.x,
                               rcs*a2.y + c2*a4.y - rcs*a6.y);
  psi[base+6*SP] = make_float2(ss*a2.x + rcs*a4.x + cc*a6.x,
                               ss*a2.y + rcs*a4.y + cc*a6.y);
  psi[base+5*SP] = make_float2(c2*a5.x - s2*a7.x, c2*a5.y - s2*a7.y);
  psi[base+7*SP] = make_float2(s2*a5.x + c2*a7.x, s2*a5.y + c2*a7.y);
}

// ---- fused (SQ_A ⊗ SQ_B) then BS, pair (0,1). G = A(5),B(5) ----
template<int SP>
__device__ __forceinline__ void sqbs_nonet(float2* __restrict__ psi, int base,
                                           const float2* __restrict__ G,
                                           float2 cs) {
  const float c = cs.x, s = cs.y;
  const float c2 = c*c - s*s, s2 = 2.f*c*s;
  const float cc = c*c, ss = s*s, rcs = SQRT2f*c*s;
  float2 A00=G[0],A02=G[1],A11=G[2],A20=G[3],A22=G[4];
  float2 B00=G[5],B02=G[6],B11=G[7],B20=G[8],B22=G[9];
  float2 v[3][3];
#pragma unroll
  for (int j = 0; j < 3; ++j)
#pragma unroll
    for (int jb = 0; jb < 3; ++jb) v[j][jb] = psi[base + j*3*SP + jb*SP];
  float2 q[9];
  {
    float2 t[3][3];
#pragma unroll
    for (int j = 0; j < 3; ++j) {
      t[j][0] = cadd(cmul(B00,v[j][0]), cmul(B02,v[j][2]));
      t[j][1] = cmul(B11,v[j][1]);
      t[j][2] = cadd(cmul(B20,v[j][0]), cmul(B22,v[j][2]));
    }
#pragma unroll
    for (int ib = 0; ib < 3; ++ib) {
      q[ib]   = cadd(cmul(A00,t[0][ib]), cmul(A02,t[2][ib]));
      q[3+ib] = cmul(A11,t[1][ib]);
      q[6+ib] = cadd(cmul(A20,t[0][ib]), cmul(A22,t[2][ib]));
    }
  }
  bs_q(q, c, s, c2, s2, cc, ss, rcs);
#pragma unroll
  for (int i = 0; i < 9; ++i) psi[base + (i/3)*3*SP + (i%3)*SP] = q[i];
}

// ---- fused (DPK_A ⊗ DPK_B dense) then BS, pair (0,1). G = A(9),B(9) ----
template<int SP>
__device__ __forceinline__ void dpbs_nonet(float2* __restrict__ psi, int base,
                                           const float2* __restrict__ G,
                                           float2 cs) {
  const float c = cs.x, s = cs.y;
  const float c2 = c*c - s*s, s2 = 2.f*c*s;
  const float cc = c*c, ss = s*s, rcs = SQRT2f*c*s;
  const float2* A = G; const float2* B = G + 9;
  float2 v[3][3];
#pragma unroll
  for (int j = 0; j < 3; ++j)
#pragma unroll
    for (int jb = 0; jb < 3; ++jb) v[j][jb] = psi[base + j*3*SP + jb*SP];
  float2 q[9];
  {
    float2 t[3][3];
#pragma unroll
    for (int j = 0; j < 3; ++j)
#pragma unroll
      for (int ib = 0; ib < 3; ++ib)
        t[j][ib] = cadd(cadd(cmul(B[ib*3+0],v[j][0]), cmul(B[ib*3+1],v[j][1])),
                        cmul(B[ib*3+2],v[j][2]));
#pragma unroll
    for (int i = 0; i < 3; ++i)
#pragma unroll
      for (int ib = 0; ib < 3; ++ib)
        q[i*3+ib] = cadd(cadd(cmul(A[i*3+0],t[0][ib]), cmul(A[i*3+1],t[1][ib])),
                         cmul(A[i*3+2],t[2][ib]));
  }
  bs_q(q, c, s, c2, s2, cc, ss, rcs);
#pragma unroll
  for (int i = 0; i < 9; ++i) psi[base + (i/3)*3*SP + (i%3)*SP] = q[i];
}

// ---- 27-amp cube sweep over free modes (hi,mid,lo); reg r = hi*9+mid*3+lo,
// amp = base + ST*r. Optional FOLD (A on mid, B on lo), then BS(mid,lo) csM,
// then BS(hi,mid) csH. FOLD: 0 none, 1 SQ (G=A5,B5), 2 dense (G=A9,B9).
template<int ST, int FOLD>
__device__ __forceinline__ void cube_sweep(float2* __restrict__ psi, int base,
                                           const float2* __restrict__ G,
                                           float2 csM, float2 csH) {
  float2 v[27];
#pragma unroll
  for (int r = 0; r < 27; ++r) v[r] = psi[base + ST*r];
  if (FOLD == 1) {
    float2 A00=G[0],A02=G[1],A11=G[2],A20=G[3],A22=G[4];
    float2 B00=G[5],B02=G[6],B11=G[7],B20=G[8],B22=G[9];
#pragma unroll
    for (int t = 0; t < 9; ++t) {          // along lo
      float2 u0=v[t*3], u2=v[t*3+2];
      v[t*3]   = cadd(cmul(B00,u0), cmul(B02,u2));
      v[t*3+1] = cmul(B11, v[t*3+1]);
      v[t*3+2] = cadd(cmul(B20,u0), cmul(B22,u2));
    }
#pragma unroll
    for (int h = 0; h < 3; ++h)
#pragma unroll
      for (int lo = 0; lo < 3; ++lo) {     // along mid
        int rb = h*9 + lo;
        float2 u0=v[rb], u2=v[rb+6];
        v[rb]   = cadd(cmul(A00,u0), cmul(A02,u2));
        v[rb+3] = cmul(A11, v[rb+3]);
        v[rb+6] = cadd(cmul(A20,u0), cmul(A22,u2));
      }
  }
  if (FOLD == 2) {
#pragma unroll
    for (int t = 0; t < 9; ++t) {          // B along lo
      float2 u0=v[t*3], u1=v[t*3+1], u2=v[t*3+2];
      v[t*3]   = cadd(cadd(cmul(G[9+0],u0),cmul(G[9+1],u1)),cmul(G[9+2],u2));
      v[t*3+1] = cadd(cadd(cmul(G[9+3],u0),cmul(G[9+4],u1)),cmul(G[9+5],u2));
      v[t*3+2] = cadd(cadd(cmul(G[9+6],u0),cmul(G[9+7],u1)),cmul(G[9+8],u2));
    }
#pragma unroll
    for (int h = 0; h < 3; ++h)
#pragma unroll
      for (int lo = 0; lo < 3; ++lo) {     // A along mid
        int rb = h*9 + lo;
        float2 u0=v[rb], u1=v[rb+3], u2=v[rb+6];
        v[rb]   = cadd(cadd(cmul(G[0],u0),cmul(G[1],u1)),cmul(G[2],u2));
        v[rb+3] = cadd(cadd(cmul(G[3],u0),cmul(G[4],u1)),cmul(G[5],u2));
        v[rb+6] = cadd(cadd(cmul(G[6],u0),cmul(G[7],u1)),cmul(G[8],u2));
      }
  }
  {
    const float c=csM.x, s=csM.y;
    const float c2=c*c-s*s, s2=2.f*c*s, cc=c*c, ss=s*s, rcs=SQRT2f*c*s;
#pragma unroll
    for (int h = 0; h < 3; ++h) bs_q(&v[h*9], c, s, c2, s2, cc, ss, rcs);
  }
  {
    const float c=csH.x, s=csH.y;
    const float c2=c*c-s*s, s2=2.f*c*s, cc=c*c, ss=s*s, rcs=SQRT2f*c*s;
#pragma unroll
    for (int lo = 0; lo < 3; ++lo) {
      float2 q[9];
#pragma unroll
      for (int j = 0; j < 9; ++j) q[j] = v[(j/3)*9 + (j%3)*3 + lo];
      bs_q(q, c, s, c2, s2, cc, ss, rcs);
#pragma unroll
      for (int j = 0; j < 9; ++j) v[(j/3)*9 + (j%3)*3 + lo] = q[j];
    }
  }
#pragma unroll
  for (int r = 0; r < 27; ++r) psi[base + ST*r] = v[r];
}

#define BASE5(g, s0,s1,s2,s3,s4) ({ int _d=(g); int _b=(_d%3)*(s0); _d/=3; \
  _b += (_d%3)*(s1); _d/=3; _b += (_d%3)*(s2); _d/=3; _b += (_d%3)*(s3); _d/=3; \
  _b += (_d%3)*(s4); _b; })

// DPK(L,mode)[i][j] = Kerr_i * U_disp[i][j] * phase^j (th2-layer phases)
__device__ __forceinline__ float2 dpk_entry(const float* __restrict__ dr,
                                            const float* __restrict__ th2,
                                            const float* __restrict__ kp,
                                            int L, int mode, int i, int j) {
  float sn, cn; sincosf(SQRT3f*dr[L*6+mode], &sn, &cn);
  float sw = sn*(1.f/SQRT3f), cw = (1.f-cn)*(1.f/3.f);
  float U;
  if      (i==0) U = (j==0) ? (1.f-cw)     : (j==1) ? (-sw)         : (SQRT2f*cw);
  else if (i==1) U = (j==0) ? (sw)         : (j==1) ? (1.f-3.f*cw)  : (-SQRT2f*sw);
  else           U = (j==0) ? (SQRT2f*cw)  : (j==1) ? (SQRT2f*sw)   : (1.f-2.f*cw);
  float2 ph = make_float2(1.f, 0.f);
  if (mode < 5) { float ps, pc; sincosf(th2[L*35+29+mode], &ps, &pc);
                  ph = make_float2(pc, ps); }
  float2 phj = (j==0) ? make_float2(1.f,0.f) : (j==1) ? ph : cmul(ph, ph);
  float ks, kc; sincosf(0.001f*kp[L*6+mode], &ks, &kc);
  float2 k1 = make_float2(kc, ks);
  float2 ki = (i==0) ? make_float2(1.f,0.f)
            : (i==1) ? k1 : cmul(cmul(k1,k1), cmul(k1,k1));
  float2 t = cmul(phj, ki);
  return make_float2(U*t.x, U*t.y);
}

// gtab (float2):
// [0,180)   BS (c,s): idx = (L*2+pass)*15 + pos (application order)
// [180,360) SQG: 180 + L*30 + c*10 : A(5) mode 2c, B(5) mode 2c+1 (th1 phases)
// [360,630) DPG: 360 + Ls*54 + c*18 : A(9) mode 2c, B(9) mode 2c+1 (layers 0..4)
// [630,684) Meas M_m = DPK(5,m)† X3 DPK(5,m): 630 + m*9 + i*3+j
// [684,690) init disp (sw,cw) per mode
__global__ __launch_bounds__(128)
void cvnn_kernel(const float* __restrict__ x,
                 const float* __restrict__ th1,
                 const float* __restrict__ th2,
                 const float* __restrict__ sr,
                 const float* __restrict__ dr,
                 const float* __restrict__ kp,
                 float* __restrict__ out) {
  __shared__ float2 psi[729];
  __shared__ float2 gtab[690];
  __shared__ float red[12];

  const int tid = threadIdx.x;
  const int bidx = blockIdx.x;

  // ---- build gate table ----
  for (int f = tid; f < 690; f += 128) {
    float sn, cn; float2 v;
    if (f < 180) {
      int Lp = f/15, pos = f%15;
      int L = Lp/2, pass = Lp%2;
      float th = (pass ? th2 : th1)[L*35 + pos];
      sincosf(th, &sn, &cn); v = make_float2(cn, sn);
    } else if (f < 360) {
      int i = f - 180; int Lc = i/10, e = i%10;
      int L = Lc/3, c3 = Lc%3;
      int mode = 2*c3 + (e >= 5); int ee = e%5;
      float Sq, Cq; sincosf(0.25f*SQRT2f*sr[L*6+mode], &Sq, &Cq);
      float2 ph = make_float2(1.f, 0.f);
      if (mode < 5) { float ps, pc; sincosf(th1[L*35+29+mode], &ps, &pc);
                      ph = make_float2(pc, ps); }
      float2 ph2 = cmul(ph, ph);
      if      (ee == 0) v = make_float2(Cq, 0.f);
      else if (ee == 1) v = make_float2(Sq*ph2.x, Sq*ph2.y);
      else if (ee == 2) v = ph;
      else if (ee == 3) v = make_float2(-Sq, 0.f);
      else              v = make_float2(Cq*ph2.x, Cq*ph2.y);
    } else if (f < 630) {
      int i = f - 360; int Ld = i/18, e = i%18;
      int Ls = Ld/3, c3 = Ld%3;
      int mode = 2*c3 + (e >= 9); int ee = e%9;
      v = dpk_entry(dr, th2, kp, Ls, mode, ee/3, ee%3);
    } else if (f < 684) {
      int i = f - 630; int m = i/9, e = i%9;
      int ii = e/3, jj = e%3;
      float2 D0i = dpk_entry(dr, th2, kp, 5, m, 0, ii);
      float2 D1i = dpk_entry(dr, th2, kp, 5, m, 1, ii);
      float2 D2i = dpk_entry(dr, th2, kp, 5, m, 2, ii);
      float2 D0j = dpk_entry(dr, th2, kp, 5, m, 0, jj);
      float2 D1j = dpk_entry(dr, th2, kp, 5, m, 1, jj);
      float2 D2j = dpk_entry(dr, th2, kp, 5, m, 2, jj);
      float2 c0 = make_float2(D0i.x, -D0i.y);
      float2 c1 = make_float2(D1i.x, -D1i.y);
      float2 c2 = make_float2(D2i.x, -D2i.y);
      float2 acc = cmul(c0, D1j);
      float2 tmp = make_float2(D0j.x + SQRT2f*D2j.x, D0j.y + SQRT2f*D2j.y);
      acc = cadd(acc, cmul(c1, tmp));
      acc = cadd(acc, cmul(c2, make_float2(SQRT2f*D1j.x, SQRT2f*D1j.y)));
      v = acc;
    } else {
      int mode = f - 684;
      sincosf(SQRT3f*x[bidx*6 + mode], &sn, &cn);
      v = make_float2(sn*(1.f/SQRT3f), (1.f-cn)*(1.f/3.f));
    }
    gtab[f] = v;
  }
  __syncthreads();

  // ---- init: product state of displaced |0> ----
  for (int idx = tid; idx < 729; idx += 128) {
    float pr = 1.f; int d = idx;
#pragma unroll
    for (int mm = 5; mm >= 0; --mm) {
      int n = d % 3; d /= 3;
      float2 dc = gtab[684 + mm];
      pr *= (n==0) ? (1.f-dc.y) : (n==1) ? dc.x : SQRT2f*dc.y;
    }
    psi[idx] = make_float2(pr, 0.f);
  }

  // ---- per-thread bases ----
  const int g = (tid < 81) ? tid : 0;      // pair(0,1) nonet id
  const int b0 = g;                        // SP=81
  const int h = (tid < 27) ? tid : 0;      // cube class id
  const int n0h = h/9, hm = (h%9)/3, hl = h%3;
  const int base123 = n0h*243 + hm*3 + hl;        // fix n0,n4,n5; ST=9
  const int base345 = n0h*243 + hm*81 + hl*27;    // fix n0,n1,n2; ST=1
  __syncthreads();

#define W81_BS(GI)      { if (tid < 81) bs_nonet<81>(psi, b0, gtab[GI]); \
    __syncthreads(); }
#define W81_SQBS(GS,GI) { if (tid < 81) sqbs_nonet<81>(psi, b0, &gtab[GS], gtab[GI]); \
    __syncthreads(); }
#define W81_DPBS(GD,GI) { if (tid < 81) dpbs_nonet<81>(psi, b0, &gtab[GD], gtab[GI]); \
    __syncthreads(); }
#define W27_123(F,GP,GI1,GI2) { if (tid < 27) \
    cube_sweep<9,F>(psi, base123, GP, gtab[GI1], gtab[GI2]); __syncthreads(); }
#define W27_345(F,GP,GI1,GI2) { if (tid < 27) \
    cube_sweep<1,F>(psi, base345, GP, gtab[GI1], gtab[GI2]); __syncthreads(); }

#pragma unroll
  for (int L = 0; L < 6; ++L) {
    {  // th1 pass (pp = 2L): folds previous layer's DPK (L>=1)
      const int PB = (L*2)*15;
      if (L == 0) {
        W81_BS(PB+0);
        W27_123(0, (const float2*)nullptr, PB+1, PB+3);
        W27_345(0, (const float2*)nullptr, PB+2, PB+4);
      } else {
        const int gd = 360 + (L-1)*54;
        W81_DPBS(gd+0, PB+0);
        W27_123(2, &gtab[gd+18], PB+1, PB+3);
        W27_345(2, &gtab[gd+36], PB+2, PB+4);
      }
      W81_BS(PB+5);
      W27_123(0, (const float2*)nullptr, PB+6, PB+8);
      W27_345(0, (const float2*)nullptr, PB+7, PB+9);
      W81_BS(PB+10);
      W27_123(0, (const float2*)nullptr, PB+11, PB+13);
      W27_345(0, (const float2*)nullptr, PB+12, PB+14);
    }
    {  // th2 pass (pp = 2L+1): folds this layer's SQ (+th1 phases)
      const int PB = (L*2+1)*15, gs = 180 + L*30;
      W81_SQBS(gs+0, PB+0);
      W27_123(1, &gtab[gs+10], PB+1, PB+3);
      W27_345(1, &gtab[gs+20], PB+2, PB+4);
      W81_BS(PB+5);
      W27_123(0, (const float2*)nullptr, PB+6, PB+8);
      W27_345(0, (const float2*)nullptr, PB+7, PB+9);
      W81_BS(PB+10);
      W27_123(0, (const float2*)nullptr, PB+11, PB+13);
      W27_345(0, (const float2*)nullptr, PB+12, PB+14);
    }
  }

  // ---- <X_m> via folded Hermitian M_m = DPK(5,m)† X DPK(5,m) ----
  float xs[6] = {0.f,0.f,0.f,0.f,0.f,0.f};
  for (int it = 0; it < 2; ++it) {
    int t = tid + (it << 7);
    if (t < 243) {
#define XACC(m, SS, BB) { int b_ = (BB); \
      const float2* M_ = &gtab[630 + (m)*9]; \
      float d0 = M_[0].x, d1 = M_[4].x, d2 = M_[8].x; \
      float2 M01 = M_[1], M02 = M_[2], M12 = M_[5]; \
      float2 a_ = psi[b_]; float2 e_ = psi[b_+(SS)]; float2 f_ = psi[b_+2*(SS)]; \
      xs[m] += d0*(a_.x*a_.x + a_.y*a_.y) + d1*(e_.x*e_.x + e_.y*e_.y) \
             + d2*(f_.x*f_.x + f_.y*f_.y) \
        + 2.f*(M01.x*(a_.x*e_.x + a_.y*e_.y) - M01.y*(a_.x*e_.y - a_.y*e_.x)) \
        + 2.f*(M02.x*(a_.x*f_.x + a_.y*f_.y) - M02.y*(a_.x*f_.y - a_.y*f_.x)) \
        + 2.f*(M12.x*(e_.x*f_.x + e_.y*f_.y) - M12.y*(e_.x*f_.y - e_.y*f_.x)); }
      XACC(0, 243, BASE5(t, 1, 3, 9, 27, 81));
      XACC(1, 81,  BASE5(t, 1, 3, 9, 27, 243));
      XACC(2, 27,  BASE5(t, 1, 3, 9, 81, 243));
      XACC(3, 9,   BASE5(t, 1, 3, 27, 81, 243));
      XACC(4, 3,   BASE5(t, 1, 9, 27, 81, 243));
      XACC(5, 1,   BASE5(t, 3, 9, 27, 81, 243));
    }
  }
  const int lane = tid & 63, wid = tid >> 6;
#pragma unroll
  for (int m = 0; m < 6; ++m) {
    float v = xs[m];
    for (int off = 32; off > 0; off >>= 1) v += __shfl_down(v, off);
    if (lane == 0) red[wid*6 + m] = v;
  }
  __syncthreads();
  if (tid < 6) out[bidx*6 + tid] = red[tid] + red[6 + tid];
}

extern "C" void kernel_launch(void* const* d_in, const int* in_sizes, int n_in,
                              void* d_out, int out_size, void* d_ws, size_t ws_size,
                              hipStream_t stream) {
  const float* x  = (const float*)d_in[0];
  const float* t1 = (const float*)d_in[1];
  const float* t2 = (const float*)d_in[2];
  const float* sr = (const float*)d_in[3];
  const float* dr = (const float*)d_in[4];
  const float* kp = (const float*)d_in[5];
  const int B = in_sizes[0] / 6;
  cvnn_kernel<<<B, 128, 0, stream>>>(x, t1, t2, sr, dr, kp, (float*)d_out);
}